// Round 1
// baseline (1353.076 us; speedup 1.0000x reference)
//
#include <hip/hip_runtime.h>

// ModulatedDeformConv (DCNv2) fused kernel — fp32 baseline.
// B=4, C=128, H=W=128, Cout=128, DG=8 (Cg=16), 3x3, stride=1, pad=1, dil=1.
// Block = 256 threads handles TP=16 consecutive output positions (one row
// segment) x all 128 couts. Two C-halves (64 ch each) staged in LDS to stay
// under 64KB static LDS (37.1 KB -> 4 blocks/CU).

#define NB    4
#define NC    128
#define NH    128
#define NW    128
#define NCOUT 128
#define NDG   8
#define NCG   16            // channels per deform group
#define NK    9
#define NCK   (NC * NK)     // 1152
#define NHW   (NH * NW)     // 16384
#define TP    16            // output positions per block
#define HALF_G   (NDG / 2)  // 4 groups per half
#define HALF_CK  576        // (64 ch)*9 per half
#define LD    580           // padded LDS row stride (580 % 32 == 4 -> 2-way max, free)
#define NTHREADS 256

__global__ __launch_bounds__(NTHREADS, 4)
void dcn_fused(const float* __restrict__ x,
               const float* __restrict__ off,
               const float* __restrict__ msk,
               const float* __restrict__ wgt,
               const float* __restrict__ bias,
               float* __restrict__ out) {
  __shared__ __align__(16) float S[TP * LD];

  const int tid  = threadIdx.x;
  const int pos0 = blockIdx.x * TP;      // linear over (b, ho, wo)
  const int b    = pos0 >> 14;           // / (128*128)
  const int ho   = (pos0 >> 7) & 127;
  const int wo0  = pos0 & 127;

  const int pos = tid & 15;              // phase-2: which position
  const int og  = tid >> 4;              // phase-2: cout group (8 couts)
  const int o0  = og * 8;

  float acc[8];
#pragma unroll
  for (int j = 0; j < 8; ++j) acc[j] = 0.f;

  for (int half = 0; half < 2; ++half) {
    if (half) __syncthreads();           // protect S before overwrite

    // ---- Phase 1: bilinear-sample channels [half*64, half*64+64) into LDS ----
    // tasks: TP(16) x HALF_G(4) x NK(9) = 576
    for (int t = tid; t < TP * HALF_G * NK; t += NTHREADS) {
      const int p   = t & 15;
      const int gkl = t >> 4;            // 0..35
      const int gl  = gkl / NK;          // 0..3 local group
      const int k   = gkl - gl * NK;     // 0..8
      const int g   = half * HALF_G + gl;
      const int gk  = g * NK + k;        // global (group, tap) channel index
      const int ky  = k / 3, kx = k - ky * 3;
      const int wo  = wo0 + p;
      const int sp  = ho * NW + wo;

      const float dy = off[((b * (2 * NDG * NK)) + gk * 2    ) * NHW + sp];
      const float dx = off[((b * (2 * NDG * NK)) + gk * 2 + 1) * NHW + sp];
      const float m  = msk[((b * (NDG * NK)) + gk) * NHW + sp];

      const float sy = dy + (float)(ho - 1 + ky);
      const float sx = dx + (float)(wo - 1 + kx);
      const float y0f = floorf(sy), x0f = floorf(sx);
      const float ly = sy - y0f, lx = sx - x0f;
      const int y0 = (int)y0f, x0i = (int)x0f;
      const int y1 = y0 + 1,  x1  = x0i + 1;
      const float hy = 1.f - ly, hx = 1.f - lx;

      float w00 = hy * hx * m;
      float w01 = hy * lx * m;
      float w10 = ly * hx * m;
      float w11 = ly * lx * m;
      if (y0  < 0 || y0  >= NH) { w00 = 0.f; w01 = 0.f; }
      if (y1  < 0 || y1  >= NH) { w10 = 0.f; w11 = 0.f; }
      if (x0i < 0 || x0i >= NW) { w00 = 0.f; w10 = 0.f; }
      if (x1  < 0 || x1  >= NW) { w01 = 0.f; w11 = 0.f; }

      const int yc0 = min(max(y0,  0), NH - 1);
      const int yc1 = min(max(y1,  0), NH - 1);
      const int xc0 = min(max(x0i, 0), NW - 1);
      const int xc1 = min(max(x1,  0), NW - 1);
      const int i00 = yc0 * NW + xc0, i01 = yc0 * NW + xc1;
      const int i10 = yc1 * NW + xc0, i11 = yc1 * NW + xc1;

      const float* xb = x + ((b * NC) + g * NCG) * NHW;
      // S layout: S[p][cl*9 + k], cl = local channel (0..63) = gl*16 + cg
      float* srow = &S[p * LD + gl * (NCG * NK) + k];
#pragma unroll
      for (int cg = 0; cg < NCG; ++cg) {
        const float* xc = xb + cg * NHW;
        srow[cg * NK] =
            w00 * xc[i00] + w01 * xc[i01] + w10 * xc[i10] + w11 * xc[i11];
      }
    }
    __syncthreads();

    // ---- Phase 2: out[pos][o0..o0+7] += S[pos][:] . W[o][:] (this half) ----
    const float* srow  = &S[pos * LD];
    const float* wbase = wgt + o0 * NCK + half * HALF_CK;
    for (int kk = 0; kk < HALF_CK; kk += 4) {
      const float4 s4 = *reinterpret_cast<const float4*>(srow + kk);
#pragma unroll
      for (int j = 0; j < 8; ++j) {
        const float4 w4 =
            *reinterpret_cast<const float4*>(wbase + j * NCK + kk);
        acc[j] += s4.x * w4.x + s4.y * w4.y + s4.z * w4.z + s4.w * w4.w;
      }
    }
  }

  const int wo = wo0 + pos;
  float* ob = out + ((b * NCOUT) + o0) * NHW + ho * NW + wo;
#pragma unroll
  for (int j = 0; j < 8; ++j) {
    ob[j * NHW] = acc[j] + bias[o0 + j];
  }
}

extern "C" void kernel_launch(void* const* d_in, const int* in_sizes, int n_in,
                              void* d_out, int out_size, void* d_ws, size_t ws_size,
                              hipStream_t stream) {
  const float* x    = (const float*)d_in[0];
  const float* off  = (const float*)d_in[1];
  const float* msk  = (const float*)d_in[2];
  const float* wgt  = (const float*)d_in[3];
  const float* bias = (const float*)d_in[4];
  float* out = (float*)d_out;

  const int nblocks = (NB * NH * NW) / TP;   // 4096
  hipLaunchKernelGGL(dcn_fused, dim3(nblocks), dim3(NTHREADS), 0, stream,
                     x, off, msk, wgt, bias, out);
}

// Round 2
// 290.335 us; speedup vs baseline: 4.6604x; 4.6604x over previous
//
#include <hip/hip_runtime.h>

// ModulatedDeformConv (DCNv2) — bf16 MFMA version.
// B=4, C=128, H=W=128, Cout=128, DG=8 (Cg=16), 3x3, stride=1, pad=1, dil=1.
//
// prep A: weight fp32 [o][c*9+k] -> bf16 [o][k*128+c]  (K-permuted; both
//         operands use the same permutation so the MFMA result is identical)
// prep B: x fp32 (B,C,H,W) -> bf16 x_t (B,DG,H,W,Cg): each bilinear corner
//         gather becomes one aligned 32B read instead of 16x 4B scattered.
// main:   per block: 16 output positions (one row segment) x all 128 couts.
//         Phase 1: sample S[16][1152] bf16 into LDS (row pad +8 -> stride
//         580 dw % 32 == 4 -> 2-way bank aliasing, free).
//         Phase 2: 4 waves x 2 tiles of mfma_f32_16x16x32_bf16, K-loop 36.

#define NB    4
#define NC    128
#define NH    128
#define NW    128
#define NCOUT 128
#define NDG   8
#define NCG   16
#define NK    9
#define NCK   1152
#define NHW   16384
#define TP    16
#define LDROW 1160            // bf16 elems per LDS row (2320 B = 580 dw)

typedef __attribute__((ext_vector_type(8))) short bf16x8;
typedef __attribute__((ext_vector_type(4))) float f32x4;

__device__ __forceinline__ unsigned pk_bf16(float a, float b) {
  // round-half-up bf16 pack (bias 2^-24 rel, negligible)
  unsigned ua = __float_as_uint(a) + 0x8000u;
  unsigned ub = __float_as_uint(b) + 0x8000u;
  return (ua >> 16) | (ub & 0xffff0000u);
}

// ---- prep A: weight fp32 [o][c*9+k] -> bf16 [o][k*128+c] ----
__global__ __launch_bounds__(256)
void wconv(const float* __restrict__ w, ushort* __restrict__ wbf) {
  int t = blockIdx.x * 256 + threadIdx.x;     // 147456 total
  int o  = t / NCK;
  int ck = t - o * NCK;
  int c  = ck / NK;
  int k  = ck - c * NK;
  unsigned u = __float_as_uint(w[t]) + 0x8000u;
  wbf[o * NCK + k * NC + c] = (ushort)(u >> 16);
}

// ---- prep B: x fp32 (B,C,H,W) -> bf16 x_t (B,DG,H,W,Cg) ----
__global__ __launch_bounds__(256)
void xtrans(const float* __restrict__ x, ushort* __restrict__ xt) {
  __shared__ ushort T[NW * NCG];              // [w][cg], 4 KB
  const int blk = blockIdx.x;                 // b*1024 + g*128 + h
  const int h = blk & 127;
  const int g = (blk >> 7) & 7;
  const int b = blk >> 10;
  const int tid = threadIdx.x;
  const float* xb = x + ((b * NC + g * NCG) * NHW) + h * NW;
#pragma unroll
  for (int i = 0; i < 8; ++i) {
    int idx = tid + 256 * i;                  // 0..2047
    int c = idx >> 7;
    int w = idx & 127;
    unsigned u = __float_as_uint(xb[c * NHW + w]) + 0x8000u;
    T[w * NCG + c] = (ushort)(u >> 16);
  }
  __syncthreads();
  const uint4* src = (const uint4*)T;
  uint4* dst = (uint4*)(xt + (((b * NDG + g) * NHW) + h * NW) * NCG);
  dst[tid] = src[tid];                        // 256 x 16B = 4 KB contiguous
}

// ---- main ----
__device__ __forceinline__ void acc_corner(const ushort* p, float wgt,
                                           float* acc) {
  const uint4* q = (const uint4*)p;           // 32B-aligned (idx*16 ushorts)
  uint4 lo = q[0], hi = q[1];
  unsigned u[8] = {lo.x, lo.y, lo.z, lo.w, hi.x, hi.y, hi.z, hi.w};
#pragma unroll
  for (int i = 0; i < 8; ++i) {
    float e0 = __uint_as_float(u[i] << 16);
    float e1 = __uint_as_float(u[i] & 0xffff0000u);
    acc[2 * i]     = fmaf(wgt, e0, acc[2 * i]);
    acc[2 * i + 1] = fmaf(wgt, e1, acc[2 * i + 1]);
  }
}

__global__ __launch_bounds__(256, 4)
void dcn_main(const float* __restrict__ off,
              const float* __restrict__ msk,
              const ushort* __restrict__ xt,   // bf16 (B,DG,H,W,Cg)
              const ushort* __restrict__ wt,   // bf16 [o][k*128+c]
              const float* __restrict__ bias,
              float* __restrict__ out) {
  __shared__ __align__(16) ushort S[TP * LDROW];   // 37,120 B

  const int tid  = threadIdx.x;
  const int pos0 = blockIdx.x * TP;
  const int b    = pos0 >> 14;
  const int ho   = (pos0 >> 7) & 127;
  const int wo0  = pos0 & 127;

  // ---- Phase 1: sample S[p][k*128 + c] (bf16) ----
  for (int t = tid; t < TP * NDG * NK; t += 256) {   // 1152 tasks
    const int p  = t & 15;
    const int gk = t >> 4;                  // g*9 + k, 0..71
    const int g  = gk / 9;
    const int k  = gk - g * 9;
    const int ky = k / 3, kx = k - ky * 3;
    const int wo = wo0 + p;
    const int sp = ho * NW + wo;

    const float dy = off[(b * 144 + gk * 2) * NHW + sp];
    const float dx = off[(b * 144 + gk * 2 + 1) * NHW + sp];
    const float m  = msk[(b * 72 + gk) * NHW + sp];

    const float sy = dy + (float)(ho - 1 + ky);
    const float sx = dx + (float)(wo - 1 + kx);
    const float y0f = floorf(sy), x0f = floorf(sx);
    const float ly = sy - y0f, lx = sx - x0f;
    const int y0 = (int)y0f, x0 = (int)x0f;
    const int y1 = y0 + 1,  x1 = x0 + 1;
    const float hy = 1.f - ly, hx = 1.f - lx;

    float w00 = hy * hx * m, w01 = hy * lx * m;
    float w10 = ly * hx * m, w11 = ly * lx * m;
    if (y0 < 0 || y0 >= NH) { w00 = 0.f; w01 = 0.f; }
    if (y1 < 0 || y1 >= NH) { w10 = 0.f; w11 = 0.f; }
    if (x0 < 0 || x0 >= NW) { w00 = 0.f; w10 = 0.f; }
    if (x1 < 0 || x1 >= NW) { w01 = 0.f; w11 = 0.f; }

    const int yc0 = min(max(y0, 0), NH - 1);
    const int yc1 = min(max(y1, 0), NH - 1);
    const int xc0 = min(max(x0, 0), NW - 1);
    const int xc1 = min(max(x1, 0), NW - 1);

    const ushort* xg = xt + (size_t)(b * NDG + g) * NHW * NCG;

    float acc[16];
#pragma unroll
    for (int i = 0; i < 16; ++i) acc[i] = 0.f;
    acc_corner(xg + (yc0 * NW + xc0) * NCG, w00, acc);
    acc_corner(xg + (yc0 * NW + xc1) * NCG, w01, acc);
    acc_corner(xg + (yc1 * NW + xc0) * NCG, w10, acc);
    acc_corner(xg + (yc1 * NW + xc1) * NCG, w11, acc);

    ushort* dstp = &S[p * LDROW + k * NC + g * NCG];  // 16B-aligned
    uint4 v0, v1;
    v0.x = pk_bf16(acc[0],  acc[1]);  v0.y = pk_bf16(acc[2],  acc[3]);
    v0.z = pk_bf16(acc[4],  acc[5]);  v0.w = pk_bf16(acc[6],  acc[7]);
    v1.x = pk_bf16(acc[8],  acc[9]);  v1.y = pk_bf16(acc[10], acc[11]);
    v1.z = pk_bf16(acc[12], acc[13]); v1.w = pk_bf16(acc[14], acc[15]);
    *(uint4*)dstp = v0;
    *((uint4*)dstp + 1) = v1;
  }
  __syncthreads();

  // ---- Phase 2: MFMA. wave wv handles couts [wv*32, wv*32+32) ----
  const int lane = tid & 63;
  const int wv   = tid >> 6;
  const int row  = lane & 15;     // pos (A row / C col-lane), see below
  const int kq   = lane >> 4;     // k-quarter

  const ushort* arow = &S[row * LDROW + kq * 8];
  const ushort* b0 = wt + (size_t)(wv * 32 + (lane & 15)) * NCK + kq * 8;
  const ushort* b1 = b0 + 16 * NCK;

  f32x4 acc0 = {0.f, 0.f, 0.f, 0.f};
  f32x4 acc1 = {0.f, 0.f, 0.f, 0.f};
  for (int kk = 0; kk < NCK; kk += 32) {
    bf16x8 a  = *(const bf16x8*)(arow + kk);
    bf16x8 w0 = *(const bf16x8*)(b0 + kk);
    bf16x8 w1 = *(const bf16x8*)(b1 + kk);
    acc0 = __builtin_amdgcn_mfma_f32_16x16x32_bf16(a, w0, acc0, 0, 0, 0);
    acc1 = __builtin_amdgcn_mfma_f32_16x16x32_bf16(a, w1, acc1, 0, 0, 0);
  }

  // C/D: col = lane&15 = cout_local, row = (lane>>4)*4 + reg = pos
  const int c0 = wv * 32 + (lane & 15);
  const float bs0 = bias[c0];
  const float bs1 = bias[c0 + 16];
  float* op0 = out + (size_t)(b * NCOUT + c0) * NHW + ho * NW + wo0 + kq * 4;
  float* op1 = op0 + 16 * NHW;
  float4 r0 = {acc0[0] + bs0, acc0[1] + bs0, acc0[2] + bs0, acc0[3] + bs0};
  float4 r1 = {acc1[0] + bs1, acc1[1] + bs1, acc1[2] + bs1, acc1[3] + bs1};
  *(float4*)op0 = r0;
  *(float4*)op1 = r1;
}

extern "C" void kernel_launch(void* const* d_in, const int* in_sizes, int n_in,
                              void* d_out, int out_size, void* d_ws, size_t ws_size,
                              hipStream_t stream) {
  const float* x    = (const float*)d_in[0];
  const float* off  = (const float*)d_in[1];
  const float* msk  = (const float*)d_in[2];
  const float* wgt  = (const float*)d_in[3];
  const float* bias = (const float*)d_in[4];
  float* out = (float*)d_out;

  ushort* xt  = (ushort*)d_ws;                         // 16,777,216 B
  ushort* wbf = xt + (size_t)NB * NDG * NHW * NCG;     // +294,912 B

  hipLaunchKernelGGL(wconv,  dim3(576),  dim3(256), 0, stream, wgt, wbf);
  hipLaunchKernelGGL(xtrans, dim3(NB * NDG * NH), dim3(256), 0, stream, x, xt);
  hipLaunchKernelGGL(dcn_main, dim3((NB * NH * NW) / TP), dim3(256), 0, stream,
                     off, msk, xt, wbf, bias, out);
}